// Round 3
// baseline (354.519 us; speedup 1.0000x reference)
//
#include <hip/hip_runtime.h>

#define BB     64
#define NPG    2048
#define TILE   128
#define CHUNKS 2
#define TPB    8              // tiles per block = NPG/(TILE*CHUNKS)
#define XP     72             // xlds pitch (bf16): 144B rows
#define TP     136            // xt/kt pitch
#define QP     104            // qlds pitch

typedef short bf16x8 __attribute__((ext_vector_type(8)));
typedef float f32x4  __attribute__((ext_vector_type(4)));
typedef unsigned short u16x8 __attribute__((ext_vector_type(8)));
typedef unsigned short u16x4 __attribute__((ext_vector_type(4)));

__device__ __forceinline__ unsigned short f2b(float f) {
    unsigned int u = __float_as_uint(f);
    return (unsigned short)((u + 0x7FFFu + ((u >> 16) & 1u)) >> 16);  // RN-even
}

__device__ __forceinline__ void stage_write(unsigned short* xlds, const float4* rx, int t) {
#pragma unroll
    for (int j = 0; j < 4; ++j) {
        int n = j * 32 + (t >> 4);
        int c = (t & 15) * 4;
        u16x4 pv = { f2b(rx[j].x), f2b(rx[j].y), f2b(rx[j].z), f2b(rx[j].w) };
        *(u16x4*)&xlds[n * XP + c] = pv;
    }
}

// decode swizzled block id: all 8 blocks (4 heads x 2 chunks) of graph b share gid%8
__device__ __forceinline__ void decode_bid(int g, int& b, int& h, int& chunk, int& bh) {
    int xcd  = g & 7;
    int rest = g >> 3;          // [0,64)
    int bhi  = rest & 7;
    h     = (rest >> 3) & 3;
    chunk = rest >> 5;
    b     = bhi * 8 + xcd;
    bh    = b * 4 + h;
}

// ---------------------------------------------------------------------------
// Kernel A: per (b,h,chunk): partial kv^T_ext[c'][d'] (80x80 f32):
//   c',d'<64: sum_n x[n,c]*k~[n,d]; row64: ksum; col64: vsum; [64][64]: count
// ---------------------------------------------------------------------------
extern "C" __global__ __launch_bounds__(512, 4)
void kv_kernel(const float* __restrict__ x,
               const float* __restrict__ Wk_w,
               const float* __restrict__ Wk_b,
               float* __restrict__ kvt)
{
    __shared__ __align__(16) unsigned short xlds[TILE * XP];
    __shared__ __align__(16) unsigned short xt[80 * TP];
    __shared__ __align__(16) unsigned short kt[80 * TP];

    const int t  = threadIdx.x;
    const int l  = t & 63;
    const int w  = t >> 6;
    const int lr = l & 15;
    const int lg = l >> 4;
    int b, h, chunk, bh;
    decode_bid(blockIdx.x, b, h, chunk, bh);

    // loop-invariant Wk A-fragments + bias
    bf16x8 wf[4][2];
    float  bias[4][4];
#pragma unroll
    for (int mt = 0; mt < 4; ++mt) {
        const float* wp = Wk_w + (size_t)(h * 64 + mt * 16 + lr) * 64;
#pragma unroll
        for (int ks = 0; ks < 2; ++ks) {
            const float* p = wp + ks * 32 + lg * 8;
            bf16x8 f;
#pragma unroll
            for (int j = 0; j < 8; ++j) f[j] = (short)f2b(p[j]);
            wf[mt][ks] = f;
        }
#pragma unroll
        for (int i = 0; i < 4; ++i) bias[mt][i] = Wk_b[h * 64 + mt * 16 + 4 * lg + i];
    }

    // rows 64..79 of xt/kt: row 64 = ones, 65..79 = zeros (persist all tiles)
    for (int idx = t; idx < 16 * TP; idx += 512) {
        int rr = idx / TP;
        int cc = idx - rr * TP;
        unsigned short v = (rr == 0 && cc < TILE) ? (unsigned short)0x3F80u : (unsigned short)0u;
        xt[(64 + rr) * TP + cc] = v;
        kt[(64 + rr) * TP + cc] = v;
    }

    // kv tile ownership: wave w owns tiles {w, w+8, w+16}; wave 0 also tile 24
    int cts[4], dts[4];
#pragma unroll
    for (int ti = 0; ti < 3; ++ti) {
        int tau = w + 8 * ti;
        int q5  = tau / 5;
        cts[ti] = q5;
        dts[ti] = tau - 5 * q5;
    }
    cts[3] = 4; dts[3] = 4;

    f32x4 kvacc[4] = {};

    const int cp = t & 63;
    const int n0 = (t >> 6) * 16;

    const float4* xg0 = (const float4*)(x + ((size_t)b * NPG + (size_t)chunk * (NPG / CHUNKS)) * 64);

    // prologue: stage tile 0
    float4 rx[4];
#pragma unroll
    for (int j = 0; j < 4; ++j) rx[j] = xg0[j * 512 + t];
    stage_write(xlds, rx, t);
    __syncthreads();

    for (int tt = 0; tt < TPB; ++tt) {
        // prefetch next tile into registers (clamped re-load on last iter)
        const int ttn = (tt + 1 < TPB) ? tt + 1 : tt;
        const float4* xg = xg0 + (size_t)ttn * TILE * 16;
#pragma unroll
        for (int j = 0; j < 4; ++j) rx[j] = xg[j * 512 + t];

        // T: transpose-fill xt[c'][n] from xlds
        {
            u16x8 w0, w1;
#pragma unroll
            for (int k2 = 0; k2 < 8; ++k2) w0[k2] = xlds[(n0 + k2) * XP + cp];
#pragma unroll
            for (int k2 = 0; k2 < 8; ++k2) w1[k2] = xlds[(n0 + 8 + k2) * XP + cp];
            *(u16x8*)&xt[cp * TP + n0]     = w0;
            *(u16x8*)&xt[cp * TP + n0 + 8] = w1;
        }

        // P: projT k^T[d][n] for this wave's 16 node-cols
        f32x4 pacc[4] = {};
        const int ncol = w * 16 + lr;
#pragma unroll
        for (int ks = 0; ks < 2; ++ks) {
            bf16x8 xb = *(const bf16x8*)&xlds[ncol * XP + ks * 32 + lg * 8];
#pragma unroll
            for (int mt = 0; mt < 4; ++mt)
                pacc[mt] = __builtin_amdgcn_mfma_f32_16x16x32_bf16(wf[mt][ks], xb, pacc[mt], 0, 0, 0);
        }
        float ss = 0.f;
#pragma unroll
        for (int mt = 0; mt < 4; ++mt)
#pragma unroll
            for (int i = 0; i < 4; ++i) {
                float v = pacc[mt][i] + bias[mt][i];
                pacc[mt][i] = v;
                ss = fmaf(v, v, ss);
            }
        ss += __shfl_xor(ss, 16, 64);
        ss += __shfl_xor(ss, 32, 64);
        float sc = rsqrtf(ss);
#pragma unroll
        for (int mt = 0; mt < 4; ++mt)
#pragma unroll
            for (int i = 0; i < 4; ++i)
                kt[(mt * 16 + 4 * lg + i) * TP + ncol] = f2b(pacc[mt][i] * sc);
        __syncthreads();

        // G: kv GEMM (reads xt/kt only)
#pragma unroll
        for (int ks = 0; ks < 4; ++ks) {
            const int ko = ks * 32 + lg * 8;
            bf16x8 a0 = *(const bf16x8*)&xt[(cts[0] * 16 + lr) * TP + ko];
            bf16x8 b0 = *(const bf16x8*)&kt[(dts[0] * 16 + lr) * TP + ko];
            kvacc[0] = __builtin_amdgcn_mfma_f32_16x16x32_bf16(a0, b0, kvacc[0], 0, 0, 0);
            bf16x8 a1 = *(const bf16x8*)&xt[(cts[1] * 16 + lr) * TP + ko];
            bf16x8 b1 = *(const bf16x8*)&kt[(dts[1] * 16 + lr) * TP + ko];
            kvacc[1] = __builtin_amdgcn_mfma_f32_16x16x32_bf16(a1, b1, kvacc[1], 0, 0, 0);
            bf16x8 a2 = *(const bf16x8*)&xt[(cts[2] * 16 + lr) * TP + ko];
            bf16x8 b2 = *(const bf16x8*)&kt[(dts[2] * 16 + lr) * TP + ko];
            kvacc[2] = __builtin_amdgcn_mfma_f32_16x16x32_bf16(a2, b2, kvacc[2], 0, 0, 0);
            if (w == 0) {
                bf16x8 a3 = *(const bf16x8*)&xt[(64 + lr) * TP + ko];
                bf16x8 b3 = *(const bf16x8*)&kt[(64 + lr) * TP + ko];
                kvacc[3] = __builtin_amdgcn_mfma_f32_16x16x32_bf16(a3, b3, kvacc[3], 0, 0, 0);
            }
        }

        // write next tile into xlds (vmcnt wait lands here, after GEMM)
        stage_write(xlds, rx, t);
        __syncthreads();
    }

    // store partial kv^T_ext
    float* base = kvt + (size_t)(chunk * 256 + bh) * 80 * 80;
#pragma unroll
    for (int ti = 0; ti < 3; ++ti) {
        float* dst = base + (size_t)(cts[ti] * 16 + 4 * lg) * 80 + dts[ti] * 16 + lr;
#pragma unroll
        for (int i = 0; i < 4; ++i) dst[i * 80] = kvacc[ti][i];
    }
    if (w == 0) {
        float* dst = base + (size_t)(64 + 4 * lg) * 80 + 64 + lr;
#pragma unroll
        for (int i = 0; i < 4; ++i) dst[i * 80] = kvacc[3][i];
    }
}

// ---------------------------------------------------------------------------
// Kernel B: per (b,h,chunk): q~ = normalize(x Wq^T + b); out = (q~_aug @ kv_ext)
// with col 64 = denominator. kv fragments = sum of the two partials.
// ---------------------------------------------------------------------------
extern "C" __global__ __launch_bounds__(512, 4)
void out_kernel(const float* __restrict__ x,
                const float* __restrict__ Wq_w,
                const float* __restrict__ Wq_b,
                const float* __restrict__ kvt,
                float* __restrict__ out)
{
    __shared__ __align__(16) unsigned short xlds[TILE * XP];
    __shared__ __align__(16) unsigned short qlds[TILE * QP];

    const int t  = threadIdx.x;
    const int l  = t & 63;
    const int w  = t >> 6;
    const int lr = l & 15;
    const int lg = l >> 4;
    int b, h, chunk, bh;
    decode_bid(blockIdx.x, b, h, chunk, bh);

    bf16x8 wf[4][2];
    float  bias[4][4];
#pragma unroll
    for (int mt = 0; mt < 4; ++mt) {
        const float* wp = Wq_w + (size_t)(h * 64 + mt * 16 + lr) * 64;
#pragma unroll
        for (int ks = 0; ks < 2; ++ks) {
            const float* p = wp + ks * 32 + lg * 8;
            bf16x8 f;
#pragma unroll
            for (int j = 0; j < 8; ++j) f[j] = (short)f2b(p[j]);
            wf[mt][ks] = f;
        }
#pragma unroll
        for (int i = 0; i < 4; ++i) bias[mt][i] = Wq_b[h * 64 + mt * 16 + 4 * lg + i];
    }

    // kv B-fragments: sum of the two chunk partials, f32 add then bf16
    bf16x8 kvf[5][3];
#pragma unroll
    for (int ct = 0; ct < 5; ++ct) {
        const float* kp0 = kvt + (size_t)bh * 6400 + (size_t)(ct * 16 + lr) * 80;
        const float* kp1 = kp0 + (size_t)256 * 6400;
#pragma unroll
        for (int ks = 0; ks < 2; ++ks) {
            const float* p0 = kp0 + ks * 32 + lg * 8;
            const float* p1 = kp1 + ks * 32 + lg * 8;
            bf16x8 f;
#pragma unroll
            for (int j = 0; j < 8; ++j) f[j] = (short)f2b(p0[j] + p1[j]);
            kvf[ct][ks] = f;
        }
        bf16x8 f2 = {0, 0, 0, 0, 0, 0, 0, 0};
        if (lg == 0) f2[0] = (short)f2b(kp0[64] + kp1[64]);
        kvf[ct][2] = f2;
    }

    // q~ columns 64..95: col 64 = 1.0, rest 0
    for (int idx = t; idx < TILE * 32; idx += 512) {
        int n  = idx >> 5;
        int cc = 64 + (idx & 31);
        qlds[n * QP + cc] = (cc == 64) ? (unsigned short)0x3F80u : (unsigned short)0u;
    }

    const float4* xg0 = (const float4*)(x + ((size_t)b * NPG + (size_t)chunk * (NPG / CHUNKS)) * 64);

    float4 rx[4];
#pragma unroll
    for (int j = 0; j < 4; ++j) rx[j] = xg0[j * 512 + t];
    stage_write(xlds, rx, t);
    __syncthreads();

    for (int tt = 0; tt < TPB; ++tt) {
        const int ttn = (tt + 1 < TPB) ? tt + 1 : tt;
        const float4* xg = xg0 + (size_t)ttn * TILE * 16;
#pragma unroll
        for (int j = 0; j < 4; ++j) rx[j] = xg[j * 512 + t];

        // P: projT q + norm, write q~ [n][d]
        f32x4 pacc[4] = {};
        const int ncol = w * 16 + lr;
#pragma unroll
        for (int ks = 0; ks < 2; ++ks) {
            bf16x8 xb = *(const bf16x8*)&xlds[ncol * XP + ks * 32 + lg * 8];
#pragma unroll
            for (int mt = 0; mt < 4; ++mt)
                pacc[mt] = __builtin_amdgcn_mfma_f32_16x16x32_bf16(wf[mt][ks], xb, pacc[mt], 0, 0, 0);
        }
        float ss = 0.f;
#pragma unroll
        for (int mt = 0; mt < 4; ++mt)
#pragma unroll
            for (int i = 0; i < 4; ++i) {
                float v = pacc[mt][i] + bias[mt][i];
                pacc[mt][i] = v;
                ss = fmaf(v, v, ss);
            }
        ss += __shfl_xor(ss, 16, 64);
        ss += __shfl_xor(ss, 32, 64);
        float sc = rsqrtf(ss);
#pragma unroll
        for (int mt = 0; mt < 4; ++mt)
#pragma unroll
            for (int i = 0; i < 4; ++i)
                qlds[ncol * QP + mt * 16 + 4 * lg + i] = f2b(pacc[mt][i] * sc);
        __syncthreads();

        // G: numerator+denominator GEMM (reads qlds only), divide, store
        f32x4 nacc[5] = {};
#pragma unroll
        for (int ks = 0; ks < 3; ++ks) {
            bf16x8 qa = *(const bf16x8*)&qlds[(w * 16 + lr) * QP + ks * 32 + lg * 8];
#pragma unroll
            for (int ct = 0; ct < 5; ++ct)
                nacc[ct] = __builtin_amdgcn_mfma_f32_16x16x32_bf16(qa, kvf[ct][ks], nacc[ct], 0, 0, 0);
        }

        const size_t nrow = (size_t)chunk * (NPG / CHUNKS) + (size_t)tt * TILE + w * 16;
        float* op = out + ((size_t)b * NPG + nrow) * 256 + h * 64;
#pragma unroll
        for (int i = 0; i < 4; ++i) {
            float den  = __shfl(nacc[4][i], (l & 48), 64);
            float rden = 1.0f / den;
#pragma unroll
            for (int ct = 0; ct < 4; ++ct)
                op[(size_t)(4 * lg + i) * 256 + ct * 16 + lr] = nacc[ct][i] * rden;
        }

        // write next tile into xlds
        stage_write(xlds, rx, t);
        __syncthreads();
    }
}

extern "C" void kernel_launch(void* const* d_in, const int* in_sizes, int n_in,
                              void* d_out, int out_size, void* d_ws, size_t ws_size,
                              hipStream_t stream) {
    const float* x    = (const float*)d_in[0];
    const float* Wq_w = (const float*)d_in[1];
    const float* Wq_b = (const float*)d_in[2];
    const float* Wk_w = (const float*)d_in[3];
    const float* Wk_b = (const float*)d_in[4];
    float* out = (float*)d_out;
    float* kvt = (float*)d_ws;   // 2 * 256 * 80 * 80 f32 = 13.1 MB scratch

    hipLaunchKernelGGL(kv_kernel,  dim3(512), dim3(512), 0, stream, x, Wk_w, Wk_b, kvt);
    hipLaunchKernelGGL(out_kernel, dim3(512), dim3(512), 0, stream, x, Wq_w, Wq_b, kvt, out);
}

// Round 4
// 224.816 us; speedup vs baseline: 1.5769x; 1.5769x over previous
//
#include <hip/hip_runtime.h>

#define NPG    2048
#define XP     72             // bf16 pitch: 144B rows, 16B-aligned
#define TP     136            // xt/kt pitch: 272B rows, 16B-aligned
#define KVTSZ  6400           // 80*80 f32 per (b,h) partial

typedef short bf16x8 __attribute__((ext_vector_type(8)));
typedef float f32x4  __attribute__((ext_vector_type(4)));
typedef unsigned short u16x8 __attribute__((ext_vector_type(8)));
typedef unsigned short u16x4 __attribute__((ext_vector_type(4)));

__device__ __forceinline__ unsigned short f2b(float f) {
    unsigned int u = __float_as_uint(f);
    return (unsigned short)((u + 0x7FFFu + ((u >> 16) & 1u)) >> 16);  // RN-even
}

// ---------------------------------------------------------------------------
// kv_kernel: 512 thr, grid 512 = (b,h,chunk2). Partial kv^T_ext[c'][d'] 80x80:
//   c',d'<64: sum_n x[n,c]*k~[n,d]; row64: ksum[d]; col64: vsum[c]
// ---------------------------------------------------------------------------
extern "C" __global__ __launch_bounds__(512, 4)
void kv_kernel(const float* __restrict__ x,
               const float* __restrict__ Wk_w,
               const float* __restrict__ Wk_b,
               float* __restrict__ kvt)
{
    __shared__ __align__(16) unsigned short wlds[64 * XP];   // Wk head rows (bf16)
    __shared__ __align__(16) unsigned short xlds[128 * XP];  // x tile [n][c]
    __shared__ __align__(16) unsigned short xt[80 * TP];     // x~^T [c'][n] (+ones row 64)
    __shared__ __align__(16) unsigned short kt[80 * TP];     // k~^T [d'][n] (+ones row 64)

    const int t  = threadIdx.x;
    const int l  = t & 63;
    const int w  = t >> 6;
    const int lr = l & 15;
    const int lg = l >> 4;
    const int g    = blockIdx.x;
    const int xcd  = g & 7;
    const int rest = g >> 3;
    const int bhi  = rest & 7;
    const int h     = (rest >> 3) & 3;
    const int chunk = rest >> 5;            // 0..1
    const int b     = bhi * 8 + xcd;
    const int bh    = b * 4 + h;

    // W head rows -> LDS (bf16)
    for (int idx = t; idx < 64 * 64; idx += 512) {
        int r = idx >> 6, c = idx & 63;
        wlds[r * XP + c] = f2b(Wk_w[(size_t)(h * 64 + r) * 64 + c]);
    }
    float bias[4][4];
#pragma unroll
    for (int mt = 0; mt < 4; ++mt)
#pragma unroll
        for (int i = 0; i < 4; ++i) bias[mt][i] = Wk_b[h * 64 + mt * 16 + 4 * lg + i];

    // aug rows 64..79 of xt/kt: row 64 = ones, rest zero
    for (int idx = t; idx < 16 * TP; idx += 512) {
        int rr = idx / TP;
        int cc = idx - rr * TP;
        unsigned short v = (rr == 0 && cc < 128) ? (unsigned short)0x3F80u : (unsigned short)0u;
        xt[(64 + rr) * TP + cc] = v;
        kt[(64 + rr) * TP + cc] = v;
    }

    // tile ownership: wave w owns tiles {w, w+8, w+16}; wave 0 also tile 24
    int cts[4], dts[4];
#pragma unroll
    for (int ti = 0; ti < 3; ++ti) {
        int tau = w + 8 * ti;
        int q5  = tau / 5;
        cts[ti] = q5;
        dts[ti] = tau - 5 * q5;
    }
    cts[3] = 4; dts[3] = 4;

    f32x4 kvacc[4] = {};
    const int cp = l | (w & 4) << 4;  // 0..63 spread: actually need full 0..63
    const int cpc = t & 63;           // transpose column c'
    const int n0  = (t >> 6) * 16;    // transpose node sub-range
    (void)cp;

    const float4* xg0 = (const float4*)(x + ((size_t)b * NPG + (size_t)chunk * 1024) * 64);

    // prologue: stage tile 0
    float4 rx[4];
#pragma unroll
    for (int j = 0; j < 4; ++j) rx[j] = xg0[j * 512 + t];
#pragma unroll
    for (int j = 0; j < 4; ++j) {
        int n = j * 32 + (t >> 4), c = (t & 15) * 4;
        u16x4 pv = { f2b(rx[j].x), f2b(rx[j].y), f2b(rx[j].z), f2b(rx[j].w) };
        *(u16x4*)&xlds[n * XP + c] = pv;
    }
    __syncthreads();

    for (int tt = 0; tt < 8; ++tt) {
        // T: transpose-fill xt[c'][n] from xlds
        {
            u16x8 w0, w1;
#pragma unroll
            for (int k2 = 0; k2 < 8; ++k2) w0[k2] = xlds[(n0 + k2) * XP + cpc];
#pragma unroll
            for (int k2 = 0; k2 < 8; ++k2) w1[k2] = xlds[(n0 + 8 + k2) * XP + cpc];
            *(u16x8*)&xt[cpc * TP + n0]     = w0;
            *(u16x8*)&xt[cpc * TP + n0 + 8] = w1;
        }

        // P: projT k^T for this wave's 16 node-cols (A-frags from wlds)
        f32x4 pacc[4] = {};
        const int ncol = w * 16 + lr;
#pragma unroll
        for (int ks = 0; ks < 2; ++ks) {
            bf16x8 xb = *(const bf16x8*)&xlds[ncol * XP + ks * 32 + lg * 8];
#pragma unroll
            for (int mt = 0; mt < 4; ++mt) {
                bf16x8 wfr = *(const bf16x8*)&wlds[(mt * 16 + lr) * XP + ks * 32 + lg * 8];
                pacc[mt] = __builtin_amdgcn_mfma_f32_16x16x32_bf16(wfr, xb, pacc[mt], 0, 0, 0);
            }
        }
        float ss = 0.f;
#pragma unroll
        for (int mt = 0; mt < 4; ++mt)
#pragma unroll
            for (int i = 0; i < 4; ++i) {
                float v = pacc[mt][i] + bias[mt][i];
                pacc[mt][i] = v;
                ss = fmaf(v, v, ss);
            }
        ss += __shfl_xor(ss, 16, 64);
        ss += __shfl_xor(ss, 32, 64);
        float sc = rsqrtf(ss);
#pragma unroll
        for (int mt = 0; mt < 4; ++mt)
#pragma unroll
            for (int i = 0; i < 4; ++i)
                kt[(mt * 16 + 4 * lg + i) * TP + ncol] = f2b(pacc[mt][i] * sc);
        __syncthreads();

        // prefetch next tile (overlaps GEMM below)
        const bool more = (tt + 1) < 8;
        if (more) {
            const float4* xg = xg0 + (size_t)(tt + 1) * 128 * 16;
#pragma unroll
            for (int j = 0; j < 4; ++j) rx[j] = xg[j * 512 + t];
        }

        // G: kv GEMM (reads xt/kt only)
#pragma unroll
        for (int ks = 0; ks < 4; ++ks) {
            const int ko = ks * 32 + lg * 8;
            bf16x8 a0 = *(const bf16x8*)&xt[(cts[0] * 16 + lr) * TP + ko];
            bf16x8 b0 = *(const bf16x8*)&kt[(dts[0] * 16 + lr) * TP + ko];
            kvacc[0] = __builtin_amdgcn_mfma_f32_16x16x32_bf16(a0, b0, kvacc[0], 0, 0, 0);
            bf16x8 a1 = *(const bf16x8*)&xt[(cts[1] * 16 + lr) * TP + ko];
            bf16x8 b1 = *(const bf16x8*)&kt[(dts[1] * 16 + lr) * TP + ko];
            kvacc[1] = __builtin_amdgcn_mfma_f32_16x16x32_bf16(a1, b1, kvacc[1], 0, 0, 0);
            bf16x8 a2 = *(const bf16x8*)&xt[(cts[2] * 16 + lr) * TP + ko];
            bf16x8 b2 = *(const bf16x8*)&kt[(dts[2] * 16 + lr) * TP + ko];
            kvacc[2] = __builtin_amdgcn_mfma_f32_16x16x32_bf16(a2, b2, kvacc[2], 0, 0, 0);
            if (w == 0) {
                bf16x8 a3 = *(const bf16x8*)&xt[(64 + lr) * TP + ko];
                bf16x8 b3 = *(const bf16x8*)&kt[(64 + lr) * TP + ko];
                kvacc[3] = __builtin_amdgcn_mfma_f32_16x16x32_bf16(a3, b3, kvacc[3], 0, 0, 0);
            }
        }

        if (more) {
#pragma unroll
            for (int j = 0; j < 4; ++j) {
                int n = j * 32 + (t >> 4), c = (t & 15) * 4;
                u16x4 pv = { f2b(rx[j].x), f2b(rx[j].y), f2b(rx[j].z), f2b(rx[j].w) };
                *(u16x4*)&xlds[n * XP + c] = pv;
            }
        }
        __syncthreads();
    }

    // store partial kv^T_ext
    float* base = kvt + (size_t)(chunk * 256 + bh) * KVTSZ;
#pragma unroll
    for (int ti = 0; ti < 3; ++ti) {
        float* dst = base + (size_t)(cts[ti] * 16 + 4 * lg) * 80 + dts[ti] * 16 + lr;
#pragma unroll
        for (int i = 0; i < 4; ++i) dst[i * 80] = kvacc[ti][i];
    }
    if (w == 0) {
        float* dst = base + (size_t)(64 + 4 * lg) * 80 + 64 + lr;
#pragma unroll
        for (int i = 0; i < 4; ++i) dst[i * 80] = kvacc[3][i];
    }
}

// ---------------------------------------------------------------------------
// out_kernel: 256 thr, grid 1024 = (b,h,chunk4). Per tile of 64 nodes:
//   q~ = normalize(x Wq^T + b); num = q~ @ kv + vsum; den = q~.ksum + n
// ---------------------------------------------------------------------------
extern "C" __global__ __launch_bounds__(256, 3)
void out_kernel(const float* __restrict__ x,
                const float* __restrict__ Wq_w,
                const float* __restrict__ Wq_b,
                const int* __restrict__ n_nodes,
                const float* __restrict__ kvt,
                float* __restrict__ out)
{
    __shared__ __align__(16) unsigned short wlds[64 * XP];
    __shared__ __align__(16) unsigned short xlds[64 * XP];
    __shared__ __align__(16) unsigned short qlds[64 * XP];

    const int t  = threadIdx.x;
    const int l  = t & 63;
    const int w  = t >> 6;          // 0..3
    const int lr = l & 15;
    const int lg = l >> 4;
    const int g    = blockIdx.x;
    const int xcd  = g & 7;
    const int rest = g >> 3;        // 0..127
    const int bhi  = rest & 7;
    const int h     = (rest >> 3) & 3;
    const int chunk = rest >> 5;    // 0..3
    const int b     = bhi * 8 + xcd;
    const int bh    = b * 4 + h;

    for (int idx = t; idx < 64 * 64; idx += 256) {
        int r = idx >> 6, c = idx & 63;
        wlds[r * XP + c] = f2b(Wq_w[(size_t)(h * 64 + r) * 64 + c]);
    }
    float bias[4][4];
#pragma unroll
    for (int mt = 0; mt < 4; ++mt)
#pragma unroll
        for (int i = 0; i < 4; ++i) bias[mt][i] = Wq_b[h * 64 + mt * 16 + 4 * lg + i];

    // kv fragments + ksum + vsum from the 2 chunk partials (f32 sum)
    const float* kp0 = kvt + (size_t)bh * KVTSZ;
    const float* kp1 = kp0 + (size_t)256 * KVTSZ;
    bf16x8 kvf[4][2];
#pragma unroll
    for (int ct = 0; ct < 4; ++ct)
#pragma unroll
        for (int ks = 0; ks < 2; ++ks) {
            const int o = (ct * 16 + lr) * 80 + ks * 32 + lg * 8;
            bf16x8 f;
#pragma unroll
            for (int j = 0; j < 8; ++j) f[j] = (short)f2b(kp0[o + j] + kp1[o + j]);
            kvf[ct][ks] = f;
        }
    float ksr[4][4];
#pragma unroll
    for (int mt = 0; mt < 4; ++mt)
#pragma unroll
        for (int i = 0; i < 4; ++i) {
            const int d = mt * 16 + 4 * lg + i;
            ksr[mt][i] = kp0[64 * 80 + d] + kp1[64 * 80 + d];
        }
    float vsr[4];
#pragma unroll
    for (int ct = 0; ct < 4; ++ct) {
        const int o = (ct * 16 + lr) * 80 + 64;
        vsr[ct] = kp0[o] + kp1[o];
    }
    const float npg = (float)n_nodes[b];

    const float4* xg0 = (const float4*)(x + ((size_t)b * NPG + (size_t)chunk * 512) * 64);

    float4 rx[4];
#pragma unroll
    for (int j = 0; j < 4; ++j) rx[j] = xg0[j * 256 + t];
#pragma unroll
    for (int j = 0; j < 4; ++j) {
        int n = j * 16 + (t >> 4), c = (t & 15) * 4;
        u16x4 pv = { f2b(rx[j].x), f2b(rx[j].y), f2b(rx[j].z), f2b(rx[j].w) };
        *(u16x4*)&xlds[n * XP + c] = pv;
    }
    __syncthreads();

    for (int tt = 0; tt < 8; ++tt) {
        // P: proj q + norm + denominator
        f32x4 pacc[4] = {};
        const int ncol = w * 16 + lr;
#pragma unroll
        for (int ks = 0; ks < 2; ++ks) {
            bf16x8 xb = *(const bf16x8*)&xlds[ncol * XP + ks * 32 + lg * 8];
#pragma unroll
            for (int mt = 0; mt < 4; ++mt) {
                bf16x8 wfr = *(const bf16x8*)&wlds[(mt * 16 + lr) * XP + ks * 32 + lg * 8];
                pacc[mt] = __builtin_amdgcn_mfma_f32_16x16x32_bf16(wfr, xb, pacc[mt], 0, 0, 0);
            }
        }
        float ss = 0.f, dd = 0.f;
#pragma unroll
        for (int mt = 0; mt < 4; ++mt)
#pragma unroll
            for (int i = 0; i < 4; ++i) {
                float v = pacc[mt][i] + bias[mt][i];
                pacc[mt][i] = v;
                ss = fmaf(v, v, ss);
                dd = fmaf(v, ksr[mt][i], dd);
            }
        ss += __shfl_xor(ss, 16, 64);
        ss += __shfl_xor(ss, 32, 64);
        dd += __shfl_xor(dd, 16, 64);
        dd += __shfl_xor(dd, 32, 64);
        float sc  = rsqrtf(ss);
        float den = fmaf(dd, sc, npg);   // q~ . ksum + n  (for node ncol)
#pragma unroll
        for (int mt = 0; mt < 4; ++mt)
#pragma unroll
            for (int i = 0; i < 4; ++i)
                qlds[ncol * XP + mt * 16 + 4 * lg + i] = f2b(pacc[mt][i] * sc);
        __syncthreads();

        const bool more = (tt + 1) < 8;
        if (more) {
            const float4* xg = xg0 + (size_t)(tt + 1) * 64 * 16;
#pragma unroll
            for (int j = 0; j < 4; ++j) rx[j] = xg[j * 256 + t];
        }

        // G: numerator GEMM over K=64
        f32x4 nacc[4] = {};
#pragma unroll
        for (int ks = 0; ks < 2; ++ks) {
            bf16x8 qa = *(const bf16x8*)&qlds[(w * 16 + lr) * XP + ks * 32 + lg * 8];
#pragma unroll
            for (int ct = 0; ct < 4; ++ct)
                nacc[ct] = __builtin_amdgcn_mfma_f32_16x16x32_bf16(qa, kvf[ct][ks], nacc[ct], 0, 0, 0);
        }

        // epilogue: +vsum, /den, store
        const size_t row0 = (size_t)b * NPG + (size_t)chunk * 512 + (size_t)tt * 64 + w * 16;
        float* op = out + row0 * 256 + h * 64;
#pragma unroll
        for (int i = 0; i < 4; ++i) {
            float den_i = __shfl(den, 4 * lg + i, 64);
            float rd = 1.0f / den_i;
#pragma unroll
            for (int ct = 0; ct < 4; ++ct)
                op[(size_t)(4 * lg + i) * 256 + ct * 16 + lr] = (nacc[ct][i] + vsr[ct]) * rd;
        }

        if (more) {
#pragma unroll
            for (int j = 0; j < 4; ++j) {
                int n = j * 16 + (t >> 4), c = (t & 15) * 4;
                u16x4 pv = { f2b(rx[j].x), f2b(rx[j].y), f2b(rx[j].z), f2b(rx[j].w) };
                *(u16x4*)&xlds[n * XP + c] = pv;
            }
        }
        __syncthreads();
    }
}

extern "C" void kernel_launch(void* const* d_in, const int* in_sizes, int n_in,
                              void* d_out, int out_size, void* d_ws, size_t ws_size,
                              hipStream_t stream) {
    const float* x     = (const float*)d_in[0];
    const float* Wq_w  = (const float*)d_in[1];
    const float* Wq_b  = (const float*)d_in[2];
    const float* Wk_w  = (const float*)d_in[3];
    const float* Wk_b  = (const float*)d_in[4];
    const int* n_nodes = (const int*)d_in[5];
    float* out = (float*)d_out;
    float* kvt = (float*)d_ws;   // 2 * 256 * 6400 f32 = 13.1 MB

    hipLaunchKernelGGL(kv_kernel,  dim3(512),  dim3(512), 0, stream, x, Wk_w, Wk_b, kvt);
    hipLaunchKernelGGL(out_kernel, dim3(1024), dim3(256), 0, stream, x, Wq_w, Wq_b, n_nodes, kvt, out);
}

// Round 5
// 223.662 us; speedup vs baseline: 1.5851x; 1.0052x over previous
//
#include <hip/hip_runtime.h>

#define NPG    2048
#define XP     72             // bf16 pitch: 144B rows, 16B-aligned
#define TP     136            // xt/kt pitch: 272B rows, 16B-aligned
#define KVTSZ  6400           // 80*80 f32 per (b,h) partial

typedef short bf16x8 __attribute__((ext_vector_type(8)));
typedef float f32x4  __attribute__((ext_vector_type(4)));
typedef unsigned short u16x8 __attribute__((ext_vector_type(8)));
typedef unsigned short u16x4 __attribute__((ext_vector_type(4)));

__device__ __forceinline__ unsigned short f2b(float f) {
    unsigned int u = __float_as_uint(f);
    return (unsigned short)((u + 0x7FFFu + ((u >> 16) & 1u)) >> 16);  // RN-even
}

// ---------------------------------------------------------------------------
// kv_kernel (unchanged from R4): 512 thr, grid 512 = (b,h,chunk2).
// Partial kv^T_ext[c'][d'] 80x80: c',d'<64: sum_n x[n,c]*k~[n,d];
// row64: ksum[d]; col64: vsum[c]
// ---------------------------------------------------------------------------
extern "C" __global__ __launch_bounds__(512, 4)
void kv_kernel(const float* __restrict__ x,
               const float* __restrict__ Wk_w,
               const float* __restrict__ Wk_b,
               float* __restrict__ kvt)
{
    __shared__ __align__(16) unsigned short wlds[64 * XP];
    __shared__ __align__(16) unsigned short xlds[128 * XP];
    __shared__ __align__(16) unsigned short xt[80 * TP];
    __shared__ __align__(16) unsigned short kt[80 * TP];

    const int t  = threadIdx.x;
    const int l  = t & 63;
    const int w  = t >> 6;
    const int lr = l & 15;
    const int lg = l >> 4;
    const int g    = blockIdx.x;
    const int xcd  = g & 7;
    const int rest = g >> 3;
    const int bhi  = rest & 7;
    const int h     = (rest >> 3) & 3;
    const int chunk = rest >> 5;
    const int b     = bhi * 8 + xcd;
    const int bh    = b * 4 + h;

    for (int idx = t; idx < 64 * 64; idx += 512) {
        int r = idx >> 6, c = idx & 63;
        wlds[r * XP + c] = f2b(Wk_w[(size_t)(h * 64 + r) * 64 + c]);
    }
    float bias[4][4];
#pragma unroll
    for (int mt = 0; mt < 4; ++mt)
#pragma unroll
        for (int i = 0; i < 4; ++i) bias[mt][i] = Wk_b[h * 64 + mt * 16 + 4 * lg + i];

    for (int idx = t; idx < 16 * TP; idx += 512) {
        int rr = idx / TP;
        int cc = idx - rr * TP;
        unsigned short v = (rr == 0 && cc < 128) ? (unsigned short)0x3F80u : (unsigned short)0u;
        xt[(64 + rr) * TP + cc] = v;
        kt[(64 + rr) * TP + cc] = v;
    }

    int cts[4], dts[4];
#pragma unroll
    for (int ti = 0; ti < 3; ++ti) {
        int tau = w + 8 * ti;
        int q5  = tau / 5;
        cts[ti] = q5;
        dts[ti] = tau - 5 * q5;
    }
    cts[3] = 4; dts[3] = 4;

    f32x4 kvacc[4] = {};
    const int cpc = t & 63;
    const int n0  = (t >> 6) * 16;

    const float4* xg0 = (const float4*)(x + ((size_t)b * NPG + (size_t)chunk * 1024) * 64);

    float4 rx[4];
#pragma unroll
    for (int j = 0; j < 4; ++j) rx[j] = xg0[j * 512 + t];
#pragma unroll
    for (int j = 0; j < 4; ++j) {
        int n = j * 32 + (t >> 4), c = (t & 15) * 4;
        u16x4 pv = { f2b(rx[j].x), f2b(rx[j].y), f2b(rx[j].z), f2b(rx[j].w) };
        *(u16x4*)&xlds[n * XP + c] = pv;
    }
    __syncthreads();

    for (int tt = 0; tt < 8; ++tt) {
        {
            u16x8 w0, w1;
#pragma unroll
            for (int k2 = 0; k2 < 8; ++k2) w0[k2] = xlds[(n0 + k2) * XP + cpc];
#pragma unroll
            for (int k2 = 0; k2 < 8; ++k2) w1[k2] = xlds[(n0 + 8 + k2) * XP + cpc];
            *(u16x8*)&xt[cpc * TP + n0]     = w0;
            *(u16x8*)&xt[cpc * TP + n0 + 8] = w1;
        }

        f32x4 pacc[4] = {};
        const int ncol = w * 16 + lr;
#pragma unroll
        for (int ks = 0; ks < 2; ++ks) {
            bf16x8 xb = *(const bf16x8*)&xlds[ncol * XP + ks * 32 + lg * 8];
#pragma unroll
            for (int mt = 0; mt < 4; ++mt) {
                bf16x8 wfr = *(const bf16x8*)&wlds[(mt * 16 + lr) * XP + ks * 32 + lg * 8];
                pacc[mt] = __builtin_amdgcn_mfma_f32_16x16x32_bf16(wfr, xb, pacc[mt], 0, 0, 0);
            }
        }
        float ss = 0.f;
#pragma unroll
        for (int mt = 0; mt < 4; ++mt)
#pragma unroll
            for (int i = 0; i < 4; ++i) {
                float v = pacc[mt][i] + bias[mt][i];
                pacc[mt][i] = v;
                ss = fmaf(v, v, ss);
            }
        ss += __shfl_xor(ss, 16, 64);
        ss += __shfl_xor(ss, 32, 64);
        float sc = rsqrtf(ss);
#pragma unroll
        for (int mt = 0; mt < 4; ++mt)
#pragma unroll
            for (int i = 0; i < 4; ++i)
                kt[(mt * 16 + 4 * lg + i) * TP + ncol] = f2b(pacc[mt][i] * sc);
        __syncthreads();

        const bool more = (tt + 1) < 8;
        if (more) {
            const float4* xg = xg0 + (size_t)(tt + 1) * 128 * 16;
#pragma unroll
            for (int j = 0; j < 4; ++j) rx[j] = xg[j * 512 + t];
        }

#pragma unroll
        for (int ks = 0; ks < 4; ++ks) {
            const int ko = ks * 32 + lg * 8;
            bf16x8 a0 = *(const bf16x8*)&xt[(cts[0] * 16 + lr) * TP + ko];
            bf16x8 b0 = *(const bf16x8*)&kt[(dts[0] * 16 + lr) * TP + ko];
            kvacc[0] = __builtin_amdgcn_mfma_f32_16x16x32_bf16(a0, b0, kvacc[0], 0, 0, 0);
            bf16x8 a1 = *(const bf16x8*)&xt[(cts[1] * 16 + lr) * TP + ko];
            bf16x8 b1 = *(const bf16x8*)&kt[(dts[1] * 16 + lr) * TP + ko];
            kvacc[1] = __builtin_amdgcn_mfma_f32_16x16x32_bf16(a1, b1, kvacc[1], 0, 0, 0);
            bf16x8 a2 = *(const bf16x8*)&xt[(cts[2] * 16 + lr) * TP + ko];
            bf16x8 b2 = *(const bf16x8*)&kt[(dts[2] * 16 + lr) * TP + ko];
            kvacc[2] = __builtin_amdgcn_mfma_f32_16x16x32_bf16(a2, b2, kvacc[2], 0, 0, 0);
            if (w == 0) {
                bf16x8 a3 = *(const bf16x8*)&xt[(64 + lr) * TP + ko];
                bf16x8 b3 = *(const bf16x8*)&kt[(64 + lr) * TP + ko];
                kvacc[3] = __builtin_amdgcn_mfma_f32_16x16x32_bf16(a3, b3, kvacc[3], 0, 0, 0);
            }
        }

        if (more) {
#pragma unroll
            for (int j = 0; j < 4; ++j) {
                int n = j * 32 + (t >> 4), c = (t & 15) * 4;
                u16x4 pv = { f2b(rx[j].x), f2b(rx[j].y), f2b(rx[j].z), f2b(rx[j].w) };
                *(u16x4*)&xlds[n * XP + c] = pv;
            }
        }
        __syncthreads();
    }

    float* base = kvt + (size_t)(chunk * 256 + bh) * KVTSZ;
#pragma unroll
    for (int ti = 0; ti < 3; ++ti) {
        float* dst = base + (size_t)(cts[ti] * 16 + 4 * lg) * 80 + dts[ti] * 16 + lr;
#pragma unroll
        for (int i = 0; i < 4; ++i) dst[i * 80] = kvacc[ti][i];
    }
    if (w == 0) {
        float* dst = base + (size_t)(64 + 4 * lg) * 80 + 64 + lr;
#pragma unroll
        for (int i = 0; i < 4; ++i) dst[i * 80] = kvacc[3][i];
    }
}

// ---------------------------------------------------------------------------
// out_kernel: barrier-free. 256 thr = 4 waves; each wave owns (b,h,128 nodes).
// Per 16-node group: x B-frags direct from global; proj MFMA; norm+den in-reg;
// C/D->A-frag butterfly (shfl over lg, same lr); GEMM vs kv frags; store.
// Block = one (b,h,quarter): 4 waves = 4 chunks of 128. W staged in LDS once.
// ---------------------------------------------------------------------------
extern "C" __global__ __launch_bounds__(256)
void out_kernel(const float* __restrict__ x,
                const float* __restrict__ Wq_w,
                const float* __restrict__ Wq_b,
                const int* __restrict__ n_nodes,
                const float* __restrict__ kvt,
                float* __restrict__ out)
{
    __shared__ __align__(16) unsigned short wlds[64 * XP];

    const int t  = threadIdx.x;
    const int l  = t & 63;
    const int w  = t >> 6;          // 0..3
    const int lr = l & 15;
    const int lg = l >> 4;
    const int g    = blockIdx.x;
    const int xcd  = g & 7;
    const int r    = g >> 3;        // 0..127
    const int bhi  = r & 7;
    const int hq   = r >> 3;        // 0..15
    const int h    = hq & 3;
    const int quarter = hq >> 2;    // 0..3
    const int b    = bhi * 8 + xcd;
    const int bh   = b * 4 + h;
    const int chunk = quarter * 4 + w;   // 0..15 -> 128 nodes

    // stage Wq head rows -> LDS (bf16), shared by the 4 same-head waves
    for (int idx = t; idx < 64 * 64; idx += 256) {
        int rr = idx >> 6, c = idx & 63;
        wlds[rr * XP + c] = f2b(Wq_w[(size_t)(h * 64 + rr) * 64 + c]);
    }
    float bias[4][4];
#pragma unroll
    for (int mt = 0; mt < 4; ++mt)
#pragma unroll
        for (int i = 0; i < 4; ++i) bias[mt][i] = Wq_b[h * 64 + mt * 16 + 4 * lg + i];

    // kv B-frags + ksum + vsum from the 2 chunk partials (f32 sum, then bf16)
    const float* kp0 = kvt + (size_t)bh * KVTSZ;
    const float* kp1 = kp0 + (size_t)256 * KVTSZ;
    bf16x8 kvf[4][2];
#pragma unroll
    for (int ct = 0; ct < 4; ++ct)
#pragma unroll
        for (int ks = 0; ks < 2; ++ks) {
            const int o = (ct * 16 + lr) * 80 + ks * 32 + lg * 8;
            bf16x8 f;
#pragma unroll
            for (int j = 0; j < 8; ++j) f[j] = (short)f2b(kp0[o + j] + kp1[o + j]);
            kvf[ct][ks] = f;
        }
    float ksr[4][4];
#pragma unroll
    for (int mt = 0; mt < 4; ++mt)
#pragma unroll
        for (int i = 0; i < 4; ++i) {
            const int d = mt * 16 + 4 * lg + i;
            ksr[mt][i] = kp0[64 * 80 + d] + kp1[64 * 80 + d];
        }
    float vsr[4];
#pragma unroll
    for (int ct = 0; ct < 4; ++ct) {
        const int o = (ct * 16 + lr) * 80 + 64;
        vsr[ct] = kp0[o] + kp1[o];
    }
    const float npg = (float)n_nodes[b];

    __syncthreads();   // wlds ready (only barrier in the kernel)

    const float* xbase = x + ((size_t)b * NPG + (size_t)chunk * 128) * 64;
    const int src0 = lr + 16 * ((lg & 1) * 2);  // butterfly source lanes
    const int src1 = src0 + 16;

    for (int gg = 0; gg < 8; ++gg) {
        // ---- x B-frags direct from global (lane (lr,lg): row base+lr) ----
        const float* xr = xbase + (size_t)(gg * 16 + lr) * 64;
        bf16x8 xb[2];
#pragma unroll
        for (int ks = 0; ks < 2; ++ks) {
            float4 p0 = *(const float4*)(xr + ks * 32 + lg * 8);
            float4 p1 = *(const float4*)(xr + ks * 32 + lg * 8 + 4);
            bf16x8 f;
            f[0] = (short)f2b(p0.x); f[1] = (short)f2b(p0.y);
            f[2] = (short)f2b(p0.z); f[3] = (short)f2b(p0.w);
            f[4] = (short)f2b(p1.x); f[5] = (short)f2b(p1.y);
            f[6] = (short)f2b(p1.z); f[7] = (short)f2b(p1.w);
            xb[ks] = f;
        }

        // ---- proj: q[d=mt*16+4lg+i][node=base+lr] ----
        f32x4 pacc[4] = {};
#pragma unroll
        for (int ks = 0; ks < 2; ++ks)
#pragma unroll
            for (int mt = 0; mt < 4; ++mt) {
                bf16x8 wfr = *(const bf16x8*)&wlds[(mt * 16 + lr) * XP + ks * 32 + lg * 8];
                pacc[mt] = __builtin_amdgcn_mfma_f32_16x16x32_bf16(wfr, xb[ks], pacc[mt], 0, 0, 0);
            }

        // ---- bias + L2 norm + denominator (per node = per lr) ----
        float ss = 0.f, dd = 0.f;
#pragma unroll
        for (int mt = 0; mt < 4; ++mt)
#pragma unroll
            for (int i = 0; i < 4; ++i) {
                float v = pacc[mt][i] + bias[mt][i];
                pacc[mt][i] = v;
                ss = fmaf(v, v, ss);
                dd = fmaf(v, ksr[mt][i], dd);
            }
        ss += __shfl_xor(ss, 16, 64);
        ss += __shfl_xor(ss, 32, 64);
        dd += __shfl_xor(dd, 16, 64);
        dd += __shfl_xor(dd, 32, 64);
        const float sc  = rsqrtf(ss);
        const float den = fmaf(dd, sc, npg);   // denominator of node base+lr

        // ---- pack q~ to bf16 pairs ----
        unsigned pw[4][2];
#pragma unroll
        for (int mt = 0; mt < 4; ++mt) {
            pw[mt][0] = (unsigned)f2b(pacc[mt][0] * sc) | ((unsigned)f2b(pacc[mt][1] * sc) << 16);
            pw[mt][1] = (unsigned)f2b(pacc[mt][2] * sc) | ((unsigned)f2b(pacc[mt][3] * sc) << 16);
        }

        // ---- butterfly: A-frag a[ks][j] = q~[node=base+lr][d=ks*32+lg*8+j] ----
        unsigned r0[4][2], r1[4][2];
#pragma unroll
        for (int mt = 0; mt < 4; ++mt)
#pragma unroll
            for (int p = 0; p < 2; ++p) {
                r0[mt][p] = __shfl(pw[mt][p], src0, 64);
                r1[mt][p] = __shfl(pw[mt][p], src1, 64);
            }
        const bool hi = (lg >> 1) & 1;   // mt = 2*ks + (lg>>1)
        union { unsigned u[4]; bf16x8 v; } a0, a1;
        a0.u[0] = hi ? r0[1][0] : r0[0][0];
        a0.u[1] = hi ? r0[1][1] : r0[0][1];
        a0.u[2] = hi ? r1[1][0] : r1[0][0];
        a0.u[3] = hi ? r1[1][1] : r1[0][1];
        a1.u[0] = hi ? r0[3][0] : r0[2][0];
        a1.u[1] = hi ? r0[3][1] : r0[2][1];
        a1.u[2] = hi ? r1[3][0] : r1[2][0];
        a1.u[3] = hi ? r1[3][1] : r1[2][1];

        // ---- numerator GEMM: rows = this wave's 16 nodes ----
        f32x4 nacc[4] = {};
#pragma unroll
        for (int ct = 0; ct < 4; ++ct) {
            nacc[ct] = __builtin_amdgcn_mfma_f32_16x16x32_bf16(a0.v, kvf[ct][0], nacc[ct], 0, 0, 0);
            nacc[ct] = __builtin_amdgcn_mfma_f32_16x16x32_bf16(a1.v, kvf[ct][1], nacc[ct], 0, 0, 0);
        }

        // ---- epilogue: +vsum, /den, store (row = 4lg+i, col = ct*16+lr) ----
        float* op = out + ((size_t)b * NPG + (size_t)chunk * 128 + gg * 16) * 256 + h * 64;
#pragma unroll
        for (int i = 0; i < 4; ++i) {
            const float den_i = __shfl(den, 4 * lg + i, 64);
            const float rd = 1.0f / den_i;
#pragma unroll
            for (int ct = 0; ct < 4; ++ct)
                op[(size_t)(4 * lg + i) * 256 + ct * 16 + lr] = (nacc[ct][i] + vsr[ct]) * rd;
        }
    }
}

extern "C" void kernel_launch(void* const* d_in, const int* in_sizes, int n_in,
                              void* d_out, int out_size, void* d_ws, size_t ws_size,
                              hipStream_t stream) {
    const float* x     = (const float*)d_in[0];
    const float* Wq_w  = (const float*)d_in[1];
    const float* Wq_b  = (const float*)d_in[2];
    const float* Wk_w  = (const float*)d_in[3];
    const float* Wk_b  = (const float*)d_in[4];
    const int* n_nodes = (const int*)d_in[5];
    float* out = (float*)d_out;
    float* kvt = (float*)d_ws;   // 2 * 256 * 6400 f32 = 13.1 MB

    hipLaunchKernelGGL(kv_kernel,  dim3(512),  dim3(512), 0, stream, x, Wk_w, Wk_b, kvt);
    hipLaunchKernelGGL(out_kernel, dim3(1024), dim3(256), 0, stream, x, Wq_w, Wq_b, n_nodes, kvt, out);
}